// Round 1
// baseline (1477.533 us; speedup 1.0000x reference)
//
#include <hip/hip_runtime.h>
#include <hip/hip_bf16.h>

#define N_NODES 50000
#define N_E0    800000
#define N_ET    850000
#define EPSBN   1e-5f

// ---- workspace layout (float offsets) ----
// A: xl buffers (128N), B: xr buffers (128N), C: outnum/activation (128N)
// S: softmax denominators (8N), STATS: BN sum/sumsq (512), P: staged f32 params
#define OFF_A 0
#define OFF_B (128*N_NODES)
#define OFF_C (256*N_NODES)
#define OFF_S (384*N_NODES)
#define OFF_STATS (392*N_NODES)
#define OFF_P (OFF_STATS + 512)
#define N_PARAM_TOT 118312
#define OFF_FLAGS (OFF_P + N_PARAM_TOT)

__device__ __forceinline__ float bf2f(unsigned short u) {
    return __uint_as_float(((unsigned int)u) << 16);
}

// ---- dtype detection: flags[0]=1 if float inputs are f32 (else bf16),
//      flags[1]=1 if edge_index is int64 (else int32) ----
__global__ void detect_kernel(const unsigned short* xr, const int* ei, int* flags) {
    __shared__ int c1, c2;
    if (threadIdx.x == 0) { c1 = 0; c2 = 0; }
    __syncthreads();
    int t = threadIdx.x;
    int l1 = 0, l2 = 0;
    for (int i = t; i < 2048; i += 256) {
        float v = bf2f(xr[i]);                 // bf16 data: |v|<~10; f32 mantissa halves: huge/NaN
        if (!(fabsf(v) <= 100.0f)) l1++;
        if (ei[2 * i + 1] != 0) l2++;          // int64 high words are all zero
    }
    atomicAdd(&c1, l1);
    atomicAdd(&c2, l2);
    __syncthreads();
    if (t == 0) {
        flags[0] = (c1 > 16) ? 1 : 0;
        flags[1] = (c2 == 0) ? 1 : 0;
    }
}

struct ParamPtrs { const void* p[23]; };

// stage all float params (x + weights) to f32 in workspace
__global__ void convert_kernel(ParamPtrs ps, float* dst, const int* flags) {
    const int sizes[23] = {100000, 256,128,256,128,128,128,128,128,
                           8192,64,8192,64,64,64,64,64,
                           128,2,128,2,2,2};
    int g = blockIdx.x * 256 + threadIdx.x;
    if (g >= N_PARAM_TOT) return;
    int t = 0, off = g;
    while (off >= sizes[t]) { off -= sizes[t]; t++; }
    float v;
    if (flags[0]) v = ((const float*)ps.p[t])[off];
    else          v = bf2f(((const unsigned short*)ps.p[t])[off]);
    dst[g] = v;
}

__device__ __forceinline__ void get_edge(const int* ei, int e, int idx64, int& src, int& dst) {
    if (e < N_E0) {
        if (idx64) { src = ei[2 * e]; dst = ei[2 * (N_E0 + e)]; }
        else       { src = ei[e];     dst = ei[N_E0 + e]; }
    } else {
        src = e - N_E0; dst = src;
    }
}

// ---- layer 1 linear: x[N,2] -> xl,xr [N,128] ----
__global__ void lin1_kernel(const float* x, const float* Wl, const float* bl,
                            const float* Wr, const float* br, float* xl, float* xr) {
    int id = blockIdx.x * 256 + threadIdx.x;   // exactly N*128
    int n = id >> 7, k = id & 127;
    float x0 = x[2 * n], x1 = x[2 * n + 1];
    xl[id] = x0 * Wl[k] + x1 * Wl[128 + k] + bl[k];
    xr[id] = x0 * Wr[k] + x1 * Wr[128 + k] + br[k];
}

// ---- layer 1 edge pass: H=8, C=16, wave per edge, float2 per lane ----
__global__ void edge1_kernel(const int* ei, const float* xl, const float* xr,
                             const float* att, float* outnum, float* s, const int* flags) {
    int gid = blockIdx.x * 256 + threadIdx.x;
    int e = gid >> 6, lane = gid & 63;
    if (e >= N_ET) return;
    int idx64 = flags[1];
    int src, dst;
    get_edge(ei, e, idx64, src, dst);
    const float2 xlv = *(const float2*)(xl + src * 128 + 2 * lane);
    const float2 xrv = *(const float2*)(xr + dst * 128 + 2 * lane);
    float z0 = xlv.x + xrv.x; z0 = z0 > 0.f ? z0 : 0.2f * z0;
    float z1 = xlv.y + xrv.y; z1 = z1 > 0.f ? z1 : 0.2f * z1;
    float part = z0 * att[2 * lane] + z1 * att[2 * lane + 1];
    part += __shfl_xor(part, 1, 64);   // butterfly sum within 8-lane head groups
    part += __shfl_xor(part, 2, 64);
    part += __shfl_xor(part, 4, 64);
    float p = __expf(part);            // no max-shift needed: logits O(1)
    atomicAdd(&outnum[dst * 128 + 2 * lane],     p * xlv.x);
    atomicAdd(&outnum[dst * 128 + 2 * lane + 1], p * xlv.y);
    if ((lane & 7) == 0) atomicAdd(&s[dst * 8 + (lane >> 3)], p);
}

// ---- BN stats (128 ch): sum & sumsq of v = outnum/s + bias ----
__global__ void stats1_kernel(const float* outnum, const float* s, const float* bias, float* stats) {
    int tid = threadIdx.x;
    int c = tid & 127, half = tid >> 7;
    float bc = bias[c];
    float sum = 0.f, sq = 0.f;
    for (int r = blockIdx.x * 2 + half; r < N_NODES; r += 240) {
        float v = outnum[r * 128 + c] / s[r * 8 + (c >> 4)] + bc;
        sum += v; sq += v * v;
    }
    __shared__ float ls[256], lq[256];
    ls[tid] = sum; lq[tid] = sq;
    __syncthreads();
    if (tid < 128) {
        atomicAdd(&stats[c],       ls[tid] + ls[tid + 128]);
        atomicAdd(&stats[128 + c], lq[tid] + lq[tid + 128]);
    }
}

__global__ void bn1_kernel(float* C, const float* s, const float* bias, const float* stats,
                           const float* g, const float* be) {
    int id = blockIdx.x * 256 + threadIdx.x;
    int n = id >> 7, k = id & 127;
    float v = C[id] / s[n * 8 + (k >> 4)] + bias[k];
    float mu = stats[k] * (1.0f / N_NODES);
    float var = stats[128 + k] * (1.0f / N_NODES) - mu * mu;
    float sc = g[k] * rsqrtf(var + EPSBN);
    float b = (v - mu) * sc + be[k];
    C[id] = b > 0.f ? b : __expf(b) - 1.f;   // ELU
}

// ---- layer 2 linear: h[N,128] @ W[128,64], 4 nodes/block via LDS ----
__global__ void lin2_kernel(const float* C, const float* Wl, const float* bl,
                            const float* Wr, const float* br, float* xl2, float* xr2) {
    __shared__ float h[512];
    int tid = threadIdx.x;
    int nb = blockIdx.x * 4;
    h[tid]       = C[nb * 128 + tid];
    h[tid + 256] = C[nb * 128 + 256 + tid];
    __syncthreads();
    int t = tid >> 6, k = tid & 63;
    float accl = bl[k], accr = br[k];
    const float* hp = h + t * 128;
    #pragma unroll 8
    for (int j = 0; j < 128; j++) {
        float hv = hp[j];
        accl += hv * Wl[j * 64 + k];
        accr += hv * Wr[j * 64 + k];
    }
    xl2[(nb + t) * 64 + k] = accl;
    xr2[(nb + t) * 64 + k] = accr;
}

// ---- layer 2 edge pass: H=4, C=16, wave per edge, 1 float per lane ----
__global__ void edge2_kernel(const int* ei, const float* xl, const float* xr,
                             const float* att, float* outnum, float* s, const int* flags) {
    int gid = blockIdx.x * 256 + threadIdx.x;
    int e = gid >> 6, lane = gid & 63;
    if (e >= N_ET) return;
    int idx64 = flags[1];
    int src, dst;
    get_edge(ei, e, idx64, src, dst);
    float xlv = xl[src * 64 + lane];
    float xrv = xr[dst * 64 + lane];
    float z = xlv + xrv; z = z > 0.f ? z : 0.2f * z;
    float part = z * att[lane];
    part += __shfl_xor(part, 1, 64);   // sum within 16-lane head groups
    part += __shfl_xor(part, 2, 64);
    part += __shfl_xor(part, 4, 64);
    part += __shfl_xor(part, 8, 64);
    float p = __expf(part);
    atomicAdd(&outnum[dst * 64 + lane], p * xlv);
    if ((lane & 15) == 0) atomicAdd(&s[dst * 4 + (lane >> 4)], p);
}

__global__ void stats2_kernel(const float* outnum, const float* s, const float* bias, float* stats) {
    int tid = threadIdx.x;
    int c = tid & 63, q = tid >> 6;
    float bc = bias[c];
    float sum = 0.f, sq = 0.f;
    for (int r = blockIdx.x * 4 + q; r < N_NODES; r += 480) {
        float v = outnum[r * 64 + c] / s[r * 4 + (c >> 4)] + bc;
        sum += v; sq += v * v;
    }
    __shared__ float ls[256], lq[256];
    ls[tid] = sum; lq[tid] = sq;
    __syncthreads();
    if (tid < 64) {
        atomicAdd(&stats[c],      ls[tid] + ls[tid + 64] + ls[tid + 128] + ls[tid + 192]);
        atomicAdd(&stats[64 + c], lq[tid] + lq[tid + 64] + lq[tid + 128] + lq[tid + 192]);
    }
}

__global__ void bn2_kernel(float* C, const float* s, const float* bias, const float* stats,
                           const float* g, const float* be) {
    int id = blockIdx.x * 256 + threadIdx.x;
    int n = id >> 6, k = id & 63;
    float v = C[id] / s[n * 4 + (k >> 4)] + bias[k];
    float mu = stats[k] * (1.0f / N_NODES);
    float var = stats[64 + k] * (1.0f / N_NODES) - mu * mu;
    float sc = g[k] * rsqrtf(var + EPSBN);
    float b = (v - mu) * sc + be[k];
    C[id] = b > 0.f ? b : __expf(b) - 1.f;
}

// ---- layer 3 linear: h[N,64] @ W[64,2] ----
__global__ void lin3_kernel(const float* C, const float* Wl, const float* bl,
                            const float* Wr, const float* br, float* xl3, float* xr3) {
    int n = blockIdx.x * 256 + threadIdx.x;
    if (n >= N_NODES) return;
    float al0 = bl[0], al1 = bl[1], ar0 = br[0], ar1 = br[1];
    #pragma unroll 8
    for (int j = 0; j < 64; j++) {
        float hv = C[n * 64 + j];
        al0 += hv * Wl[2 * j]; al1 += hv * Wl[2 * j + 1];
        ar0 += hv * Wr[2 * j]; ar1 += hv * Wr[2 * j + 1];
    }
    xl3[2 * n] = al0; xl3[2 * n + 1] = al1;
    xr3[2 * n] = ar0; xr3[2 * n + 1] = ar1;
}

// ---- layer 3 edge pass: H=1, C=2, thread per edge ----
__global__ void edge3_kernel(const int* ei, const float* xl, const float* xr,
                             const float* att, float* outnum, float* s, const int* flags) {
    int e = blockIdx.x * 256 + threadIdx.x;
    if (e >= N_ET) return;
    int idx64 = flags[1];
    int src, dst;
    get_edge(ei, e, idx64, src, dst);
    float xl0 = xl[2 * src], xl1 = xl[2 * src + 1];
    float xr0 = xr[2 * dst], xr1 = xr[2 * dst + 1];
    float z0 = xl0 + xr0; z0 = z0 > 0.f ? z0 : 0.2f * z0;
    float z1 = xl1 + xr1; z1 = z1 > 0.f ? z1 : 0.2f * z1;
    float p = __expf(z0 * att[0] + z1 * att[1]);
    atomicAdd(&outnum[2 * dst],     p * xl0);
    atomicAdd(&outnum[2 * dst + 1], p * xl1);
    atomicAdd(&s[dst], p);
}

__global__ void out_kernel(const float* outnum, const float* s, const float* bias,
                           void* out, const int* flags) {
    int id = blockIdx.x * 256 + threadIdx.x;
    if (id >= 2 * N_NODES) return;
    int n = id >> 1, c = id & 1;
    float v = outnum[id] / s[n] + bias[c];
    if (flags[0]) ((float*)out)[id] = v;
    else ((__hip_bfloat16*)out)[id] = __float2bfloat16(v);
}

extern "C" void kernel_launch(void* const* d_in, const int* in_sizes, int n_in,
                              void* d_out, int out_size, void* d_ws, size_t ws_size,
                              hipStream_t stream) {
    float* W = (float*)d_ws;
    float* A = W + OFF_A;
    float* B = W + OFF_B;
    float* C = W + OFF_C;
    float* S = W + OFF_S;
    float* STATS = W + OFF_STATS;
    float* P = W + OFF_P;
    int* FLAGS = (int*)(W + OFF_FLAGS);

    const int* ei = (const int*)d_in[1];

    // staged f32 param pointers (order matches convert_kernel's sizes table)
    float* Px    = P;
    float* W1l = Px + 100000; float* b1l = W1l + 256; float* W1r = b1l + 128; float* b1r = W1r + 256;
    float* a1  = b1r + 128;   float* bias1 = a1 + 128; float* g1 = bias1 + 128; float* be1 = g1 + 128;
    float* W2l = be1 + 128;   float* b2l = W2l + 8192; float* W2r = b2l + 64;  float* b2r = W2r + 8192;
    float* a2  = b2r + 64;    float* bias2 = a2 + 64;  float* g2 = bias2 + 64; float* be2 = g2 + 64;
    float* W3l = be2 + 64;    float* b3l = W3l + 128;  float* W3r = b3l + 2;   float* b3r = W3r + 128;
    float* a3  = b3r + 2;     float* bias3 = a3 + 2;

    detect_kernel<<<1, 256, 0, stream>>>((const unsigned short*)d_in[0], ei, FLAGS);

    ParamPtrs ps;
    ps.p[0] = d_in[0];
    for (int j = 1; j < 23; j++) ps.p[j] = d_in[j + 1];
    convert_kernel<<<(N_PARAM_TOT + 255) / 256, 256, 0, stream>>>(ps, P, FLAGS);

    // ---- layer 1 ----
    hipMemsetAsync(C, 0, (size_t)128 * N_NODES * 4, stream);
    hipMemsetAsync(S, 0, ((size_t)8 * N_NODES + 512) * 4, stream);
    lin1_kernel<<<N_NODES * 128 / 256, 256, 0, stream>>>(Px, W1l, b1l, W1r, b1r, A, B);
    edge1_kernel<<<N_ET * 64 / 256, 256, 0, stream>>>(ei, A, B, a1, C, S, FLAGS);
    stats1_kernel<<<120, 256, 0, stream>>>(C, S, bias1, STATS);
    bn1_kernel<<<N_NODES * 128 / 256, 256, 0, stream>>>(C, S, bias1, STATS, g1, be1);

    // ---- layer 2 ----
    lin2_kernel<<<N_NODES / 4, 256, 0, stream>>>(C, W2l, b2l, W2r, b2r, A, B);
    hipMemsetAsync(C, 0, (size_t)64 * N_NODES * 4, stream);
    hipMemsetAsync(S, 0, ((size_t)8 * N_NODES + 512) * 4, stream);
    edge2_kernel<<<N_ET * 64 / 256, 256, 0, stream>>>(ei, A, B, a2, C, S, FLAGS);
    stats2_kernel<<<120, 256, 0, stream>>>(C, S, bias2, STATS);
    bn2_kernel<<<N_NODES * 64 / 256, 256, 0, stream>>>(C, S, bias2, STATS, g2, be2);

    // ---- layer 3 ----
    lin3_kernel<<<(N_NODES + 255) / 256, 256, 0, stream>>>(C, W3l, b3l, W3r, b3r, A, B);
    hipMemsetAsync(C, 0, (size_t)2 * N_NODES * 4, stream);
    hipMemsetAsync(S, 0, ((size_t)8 * N_NODES + 512) * 4, stream);
    edge3_kernel<<<(N_ET + 255) / 256, 256, 0, stream>>>(ei, A, B, a3, C, S, FLAGS);
    out_kernel<<<(2 * N_NODES + 255) / 256, 256, 0, stream>>>(C, S, bias3, d_out, FLAGS);
}

// Round 2
// 557.156 us; speedup vs baseline: 2.6519x; 2.6519x over previous
//
#include <hip/hip_runtime.h>
#include <hip/hip_bf16.h>

#define N_NODES 50000
#define N_E0    800000
#define N_ET    850000
#define EPSBN   1e-5f

// ---- workspace layout (32-bit word offsets) ----
// C: activations (128N), A/B: xl/xr tables for layers 2/3 (64N each)
// STATS: 512 (layer1 uses [0..255], layer2 uses [256..383])
// P: staged f32 params, then int CSR arrays
#define OFF_C 0
#define OFF_A (128*N_NODES)
#define OFF_B (192*N_NODES)
#define OFF_STATS (256*N_NODES)
#define OFF_P (OFF_STATS + 512)
#define N_PARAM_TOT 118312
#define OFF_ROWPTR (OFF_P + N_PARAM_TOT)      // 50001 ints
#define OFF_DEG    (OFF_ROWPTR + 50001)       // 50000 ints
#define OFF_CURSOR (OFF_DEG + 50000)          // 50000 ints
#define OFF_BSUM   (OFF_CURSOR + 50000)       // 256 ints
#define OFF_COL    (OFF_BSUM + 256)           // 850000 ints
#define OFF_FLAGS  (OFF_COL + 850000)         // 2 ints

__device__ __forceinline__ float bf2f(unsigned short u) {
    return __uint_as_float(((unsigned int)u) << 16);
}

// ---- dtype detection: flags[0]=1 if float inputs are f32 (else bf16),
//      flags[1]=1 if edge_index is int64 (else int32) ----
__global__ void detect_kernel(const unsigned short* xr, const int* ei, int* flags) {
    __shared__ int c1, c2;
    if (threadIdx.x == 0) { c1 = 0; c2 = 0; }
    __syncthreads();
    int t = threadIdx.x;
    int l1 = 0, l2 = 0;
    for (int i = t; i < 2048; i += 256) {
        float v = bf2f(xr[i]);
        if (!(fabsf(v) <= 100.0f)) l1++;
        if (ei[2 * i + 1] != 0) l2++;
    }
    atomicAdd(&c1, l1);
    atomicAdd(&c2, l2);
    __syncthreads();
    if (t == 0) {
        flags[0] = (c1 > 16) ? 1 : 0;
        flags[1] = (c2 == 0) ? 1 : 0;
    }
}

struct ParamPtrs { const void* p[23]; };

__global__ void convert_kernel(ParamPtrs ps, float* dst, const int* flags) {
    const int sizes[23] = {100000, 256,128,256,128,128,128,128,128,
                           8192,64,8192,64,64,64,64,64,
                           128,2,128,2,2,2};
    int g = blockIdx.x * 256 + threadIdx.x;
    if (g >= N_PARAM_TOT) return;
    int t = 0, off = g;
    while (off >= sizes[t]) { off -= sizes[t]; t++; }
    float v;
    if (flags[0]) v = ((const float*)ps.p[t])[off];
    else          v = bf2f(((const unsigned short*)ps.p[t])[off]);
    dst[g] = v;
}

// ---- CSR build ----
__global__ void init_kernel(int* deg, float* stats) {
    int i = blockIdx.x * 256 + threadIdx.x;
    if (i < N_NODES) deg[i] = 1;            // self-loop pre-counted
    if (i < 512) stats[i] = 0.f;
}

__global__ void hist_kernel(const int* ei, int* deg, const int* flags) {
    int e = blockIdx.x * 256 + threadIdx.x;
    if (e >= N_E0) return;
    int dst = flags[1] ? ei[2 * (N_E0 + e)] : ei[N_E0 + e];
    atomicAdd(&deg[dst], 1);
}

__global__ void scan1_kernel(const int* deg, int* row_ptr, int* bsum) {
    __shared__ int sh[256];
    int i = blockIdx.x * 256 + threadIdx.x;
    int v = (i < N_NODES) ? deg[i] : 0;
    sh[threadIdx.x] = v;
    __syncthreads();
    for (int off = 1; off < 256; off <<= 1) {
        int t = (threadIdx.x >= off) ? sh[threadIdx.x - off] : 0;
        __syncthreads();
        sh[threadIdx.x] += t;
        __syncthreads();
    }
    if (i < N_NODES) row_ptr[i] = sh[threadIdx.x] - v;   // exclusive within block
    if (threadIdx.x == 255) bsum[blockIdx.x] = sh[255];
}

__global__ void scan2_kernel(int* bsum) {
    __shared__ int sh[256];
    int t = threadIdx.x;
    int v = (t < 196) ? bsum[t] : 0;
    sh[t] = v;
    __syncthreads();
    for (int off = 1; off < 256; off <<= 1) {
        int u = (t >= off) ? sh[t - off] : 0;
        __syncthreads();
        sh[t] += u;
        __syncthreads();
    }
    bsum[t] = sh[t] - v;   // exclusive
}

__global__ void scan3_kernel(int* row_ptr, int* cursor, const int* bsum) {
    int i = blockIdx.x * 256 + threadIdx.x;
    if (i < N_NODES) {
        int r = row_ptr[i] + bsum[blockIdx.x];
        row_ptr[i] = r;
        cursor[i] = r;
    }
    if (i == 0) row_ptr[N_NODES] = N_ET;
}

__global__ void scatter_kernel(const int* ei, int* cursor, int* col, const int* flags) {
    int e = blockIdx.x * 256 + threadIdx.x;
    if (e >= N_ET) return;
    int src, dst;
    if (e < N_E0) {
        int i64 = flags[1];
        if (i64) { src = ei[2 * e]; dst = ei[2 * (N_E0 + e)]; }
        else     { src = ei[e];     dst = ei[N_E0 + e]; }
    } else {
        src = dst = e - N_E0;
    }
    int pos = atomicAdd(&cursor[dst], 1);
    col[pos] = src;
}

// ---- layer 1 gather: H=8, C=16; wave/node, float2 per lane.
// xl/xr recomputed on the fly from x (in-dim=2) -> no feature tables, no atomics.
__global__ void __launch_bounds__(256) gather1_kernel(
    const int* row_ptr, const int* col, const float* x,
    const float* W1l, const float* b1l, const float* W1r, const float* b1r,
    const float* att, const float* bias, float* C)
{
    int gid = blockIdx.x * 256 + threadIdx.x;
    int n = gid >> 6;
    int lane = threadIdx.x & 63;
    if (n >= N_NODES) return;
    float2 wl0 = *(const float2*)(W1l + 2 * lane);          // row-0 coefs (ch pair)
    float2 wl1 = *(const float2*)(W1l + 128 + 2 * lane);    // row-1 coefs
    float2 bl  = *(const float2*)(b1l + 2 * lane);
    float2 wr0 = *(const float2*)(W1r + 2 * lane);
    float2 wr1 = *(const float2*)(W1r + 128 + 2 * lane);
    float2 br  = *(const float2*)(b1r + 2 * lane);
    float2 at  = *(const float2*)(att + 2 * lane);
    float2 xd  = *(const float2*)(x + 2 * n);
    float xr0 = xd.x * wr0.x + xd.y * wr1.x + br.x;
    float xr1 = xd.x * wr0.y + xd.y * wr1.y + br.y;
    int base = row_ptr[n];
    int deg  = row_ptr[n + 1] - base;
    float acc0 = 0.f, acc1 = 0.f, den = 0.f;
    for (int j0 = 0; j0 < deg; j0 += 64) {
        int idx = j0 + lane;
        int msrc = (idx < deg) ? col[base + idx] : 0;
        int cnt = deg - j0; if (cnt > 64) cnt = 64;
        for (int j = 0; j < cnt; ++j) {
            int src = __shfl(msrc, j, 64);
            float2 xs = *(const float2*)(x + 2 * src);
            float xl0 = xs.x * wl0.x + xs.y * wl1.x + bl.x;
            float xl1 = xs.x * wl0.y + xs.y * wl1.y + bl.y;
            float z0 = xl0 + xr0; z0 = fmaxf(z0, 0.f) + 0.2f * fminf(z0, 0.f);
            float z1 = xl1 + xr1; z1 = fmaxf(z1, 0.f) + 0.2f * fminf(z1, 0.f);
            float part = z0 * at.x + z1 * at.y;
            part += __shfl_xor(part, 1, 64);   // reduce within 8-lane head group
            part += __shfl_xor(part, 2, 64);
            part += __shfl_xor(part, 4, 64);
            float p = __expf(part);            // logits O(1): no max-shift needed
            acc0 += p * xl0; acc1 += p * xl1; den += p;
        }
    }
    float inv = 1.f / den;
    float2 bi = *(const float2*)(bias + 2 * lane);
    float2 outv; outv.x = acc0 * inv + bi.x; outv.y = acc1 * inv + bi.y;
    *(float2*)(C + n * 128 + 2 * lane) = outv;
}

// ---- BN stats + apply (layer 1, 128 ch) ----
__global__ void stats1_kernel(const float* C, float* stats) {
    int tid = threadIdx.x;
    int c = tid & 127, half = tid >> 7;
    float sum = 0.f, sq = 0.f;
    for (int r = blockIdx.x * 2 + half; r < N_NODES; r += 240) {
        float v = C[r * 128 + c];
        sum += v; sq += v * v;
    }
    __shared__ float ls[256], lq[256];
    ls[tid] = sum; lq[tid] = sq;
    __syncthreads();
    if (tid < 128) {
        atomicAdd(&stats[c],       ls[tid] + ls[tid + 128]);
        atomicAdd(&stats[128 + c], lq[tid] + lq[tid + 128]);
    }
}

__global__ void bn1_kernel(float* C, const float* stats, const float* g, const float* be) {
    int id = blockIdx.x * 256 + threadIdx.x;
    int k = id & 127;
    float v = C[id];
    float mu = stats[k] * (1.0f / N_NODES);
    float var = stats[128 + k] * (1.0f / N_NODES) - mu * mu;
    float sc = g[k] * rsqrtf(var + EPSBN);
    float b = (v - mu) * sc + be[k];
    C[id] = b > 0.f ? b : __expf(b) - 1.f;   // ELU
}

// ---- layer 2 linear: h[N,128] @ W[128,64] x2, 4 nodes/block via LDS ----
__global__ void lin2_kernel(const float* C, const float* Wl, const float* bl,
                            const float* Wr, const float* br, float* xl2, float* xr2) {
    __shared__ float h[512];
    int tid = threadIdx.x;
    int nb = blockIdx.x * 4;
    h[tid]       = C[nb * 128 + tid];
    h[tid + 256] = C[nb * 128 + 256 + tid];
    __syncthreads();
    int t = tid >> 6, k = tid & 63;
    float accl = bl[k], accr = br[k];
    const float* hp = h + t * 128;
    #pragma unroll 8
    for (int j = 0; j < 128; j++) {
        float hv = hp[j];
        accl += hv * Wl[j * 64 + k];
        accr += hv * Wr[j * 64 + k];
    }
    xl2[(nb + t) * 64 + k] = accl;
    xr2[(nb + t) * 64 + k] = accr;
}

// ---- layer 2 gather: H=4, C=16; wave/node, 1 float per lane ----
__global__ void __launch_bounds__(256) gather2_kernel(
    const int* row_ptr, const int* col, const float* xl2, const float* xr2,
    const float* att, const float* bias, float* C)
{
    int gid = blockIdx.x * 256 + threadIdx.x;
    int n = gid >> 6;
    int lane = threadIdx.x & 63;
    if (n >= N_NODES) return;
    float xrv = xr2[n * 64 + lane];
    float atv = att[lane];
    int base = row_ptr[n];
    int deg  = row_ptr[n + 1] - base;
    float acc = 0.f, den = 0.f;
    for (int j0 = 0; j0 < deg; j0 += 64) {
        int idx = j0 + lane;
        int msrc = (idx < deg) ? col[base + idx] : 0;
        int cnt = deg - j0; if (cnt > 64) cnt = 64;
        for (int j = 0; j < cnt; ++j) {
            int src = __shfl(msrc, j, 64);
            float xlv = xl2[src * 64 + lane];
            float z = xlv + xrv; z = fmaxf(z, 0.f) + 0.2f * fminf(z, 0.f);
            float part = z * atv;
            part += __shfl_xor(part, 1, 64);   // reduce within 16-lane head group
            part += __shfl_xor(part, 2, 64);
            part += __shfl_xor(part, 4, 64);
            part += __shfl_xor(part, 8, 64);
            float p = __expf(part);
            acc += p * xlv; den += p;
        }
    }
    C[n * 64 + lane] = acc / den + bias[lane];
}

__global__ void stats2_kernel(const float* C, float* stats) {
    int tid = threadIdx.x;
    int c = tid & 63, q = tid >> 6;
    float sum = 0.f, sq = 0.f;
    for (int r = blockIdx.x * 4 + q; r < N_NODES; r += 480) {
        float v = C[r * 64 + c];
        sum += v; sq += v * v;
    }
    __shared__ float ls[256], lq[256];
    ls[tid] = sum; lq[tid] = sq;
    __syncthreads();
    if (tid < 64) {
        atomicAdd(&stats[c],      ls[tid] + ls[tid + 64] + ls[tid + 128] + ls[tid + 192]);
        atomicAdd(&stats[64 + c], lq[tid] + lq[tid + 64] + lq[tid + 128] + lq[tid + 192]);
    }
}

__global__ void bn2_kernel(float* C, const float* stats, const float* g, const float* be) {
    int id = blockIdx.x * 256 + threadIdx.x;
    int k = id & 63;
    float v = C[id];
    float mu = stats[k] * (1.0f / N_NODES);
    float var = stats[64 + k] * (1.0f / N_NODES) - mu * mu;
    float sc = g[k] * rsqrtf(var + EPSBN);
    float b = (v - mu) * sc + be[k];
    C[id] = b > 0.f ? b : __expf(b) - 1.f;
}

// ---- layer 3 linear: h[N,64] @ W[64,2] x2 ----
__global__ void lin3_kernel(const float* C, const float* Wl, const float* bl,
                            const float* Wr, const float* br, float* xl3, float* xr3) {
    int n = blockIdx.x * 256 + threadIdx.x;
    if (n >= N_NODES) return;
    float al0 = bl[0], al1 = bl[1], ar0 = br[0], ar1 = br[1];
    #pragma unroll 8
    for (int j = 0; j < 64; j++) {
        float hv = C[n * 64 + j];
        al0 += hv * Wl[2 * j]; al1 += hv * Wl[2 * j + 1];
        ar0 += hv * Wr[2 * j]; ar1 += hv * Wr[2 * j + 1];
    }
    xl3[2 * n] = al0; xl3[2 * n + 1] = al1;
    xr3[2 * n] = ar0; xr3[2 * n + 1] = ar1;
}

// ---- layer 3 gather: H=1, C=2; thread/node, fused output write ----
__global__ void gather3_kernel(const int* row_ptr, const int* col,
                               const float* xl3, const float* xr3,
                               const float* att, const float* bias,
                               void* out, const int* flags) {
    int n = blockIdx.x * 256 + threadIdx.x;
    if (n >= N_NODES) return;
    float a0 = att[0], a1 = att[1];
    float xr0 = xr3[2 * n], xr1 = xr3[2 * n + 1];
    float acc0 = 0.f, acc1 = 0.f, den = 0.f;
    int e0 = row_ptr[n], e1 = row_ptr[n + 1];
    for (int e = e0; e < e1; ++e) {
        int src = col[e];
        float2 xs = *(const float2*)(xl3 + 2 * src);
        float z0 = xs.x + xr0; z0 = fmaxf(z0, 0.f) + 0.2f * fminf(z0, 0.f);
        float z1 = xs.y + xr1; z1 = fmaxf(z1, 0.f) + 0.2f * fminf(z1, 0.f);
        float p = __expf(z0 * a0 + z1 * a1);
        acc0 += p * xs.x; acc1 += p * xs.y; den += p;
    }
    float inv = 1.f / den;
    float v0 = acc0 * inv + bias[0];
    float v1 = acc1 * inv + bias[1];
    if (flags[0]) {
        ((float*)out)[2 * n] = v0;
        ((float*)out)[2 * n + 1] = v1;
    } else {
        ((__hip_bfloat16*)out)[2 * n] = __float2bfloat16(v0);
        ((__hip_bfloat16*)out)[2 * n + 1] = __float2bfloat16(v1);
    }
}

extern "C" void kernel_launch(void* const* d_in, const int* in_sizes, int n_in,
                              void* d_out, int out_size, void* d_ws, size_t ws_size,
                              hipStream_t stream) {
    float* W = (float*)d_ws;
    float* C = W + OFF_C;
    float* A = W + OFF_A;
    float* B = W + OFF_B;
    float* STATS = W + OFF_STATS;
    float* P = W + OFF_P;
    int* ROWPTR = (int*)(W + OFF_ROWPTR);
    int* DEG    = (int*)(W + OFF_DEG);
    int* CURSOR = (int*)(W + OFF_CURSOR);
    int* BSUM   = (int*)(W + OFF_BSUM);
    int* COL    = (int*)(W + OFF_COL);
    int* FLAGS  = (int*)(W + OFF_FLAGS);

    const int* ei = (const int*)d_in[1];

    // staged f32 param pointers (order matches convert_kernel's sizes table)
    float* Px  = P;
    float* W1l = Px + 100000; float* b1l = W1l + 256; float* W1r = b1l + 128; float* b1r = W1r + 256;
    float* a1  = b1r + 128;   float* bias1 = a1 + 128; float* g1 = bias1 + 128; float* be1 = g1 + 128;
    float* W2l = be1 + 128;   float* b2l = W2l + 8192; float* W2r = b2l + 64;  float* b2r = W2r + 8192;
    float* a2  = b2r + 64;    float* bias2 = a2 + 64;  float* g2 = bias2 + 64; float* be2 = g2 + 64;
    float* W3l = be2 + 64;    float* b3l = W3l + 128;  float* W3r = b3l + 2;   float* b3r = W3r + 128;
    float* a3  = b3r + 2;     float* bias3 = a3 + 2;

    detect_kernel<<<1, 256, 0, stream>>>((const unsigned short*)d_in[0], ei, FLAGS);

    ParamPtrs ps;
    ps.p[0] = d_in[0];
    for (int j = 1; j < 23; j++) ps.p[j] = d_in[j + 1];
    convert_kernel<<<(N_PARAM_TOT + 255) / 256, 256, 0, stream>>>(ps, P, FLAGS);

    // ---- CSR build (reused by all 3 layers) ----
    init_kernel<<<196, 256, 0, stream>>>(DEG, STATS);
    hist_kernel<<<(N_E0 + 255) / 256, 256, 0, stream>>>(ei, DEG, FLAGS);
    scan1_kernel<<<196, 256, 0, stream>>>(DEG, ROWPTR, BSUM);
    scan2_kernel<<<1, 256, 0, stream>>>(BSUM);
    scan3_kernel<<<196, 256, 0, stream>>>(ROWPTR, CURSOR, BSUM);
    scatter_kernel<<<(N_ET + 255) / 256, 256, 0, stream>>>(ei, CURSOR, COL, FLAGS);

    // ---- layer 1 ----
    gather1_kernel<<<N_NODES * 64 / 256, 256, 0, stream>>>(ROWPTR, COL, Px, W1l, b1l, W1r, b1r, a1, bias1, C);
    stats1_kernel<<<120, 256, 0, stream>>>(C, STATS);
    bn1_kernel<<<N_NODES * 128 / 256, 256, 0, stream>>>(C, STATS, g1, be1);

    // ---- layer 2 ----
    lin2_kernel<<<N_NODES / 4, 256, 0, stream>>>(C, W2l, b2l, W2r, b2r, A, B);
    gather2_kernel<<<N_NODES * 64 / 256, 256, 0, stream>>>(ROWPTR, COL, A, B, a2, bias2, C);
    stats2_kernel<<<120, 256, 0, stream>>>(C, STATS + 256);
    bn2_kernel<<<N_NODES * 64 / 256, 256, 0, stream>>>(C, STATS + 256, g2, be2);

    // ---- layer 3 ----
    lin3_kernel<<<196, 256, 0, stream>>>(C, W3l, b3l, W3r, b3r, A, B);
    gather3_kernel<<<196, 256, 0, stream>>>(ROWPTR, COL, A, B, a3, bias3, d_out, FLAGS);
}

// Round 3
// 453.836 us; speedup vs baseline: 3.2557x; 1.2277x over previous
//
#include <hip/hip_runtime.h>
#include <hip/hip_bf16.h>

#define N_NODES 50000
#define N_E0    800000
#define N_ET    850000
#define EPSBN   1e-5f

// ---- workspace layout (32-bit word offsets) ----
#define OFF_C 0
#define OFF_A (128*N_NODES)
#define OFF_B (192*N_NODES)
#define OFF_STATS (256*N_NODES)
#define OFF_P (OFF_STATS + 512)
#define N_PARAM_TOT 118312
#define OFF_ROWPTR (OFF_P + N_PARAM_TOT)      // 50001 ints
#define OFF_DEG    (OFF_ROWPTR + 50001)       // 50000 ints
#define OFF_CURSOR (OFF_DEG + 50000)          // 50000 ints
#define OFF_BSUM   (OFF_CURSOR + 50000)       // 256 ints
#define OFF_COL    (OFF_BSUM + 256)           // 850000 ints
#define OFF_FLAGS  (OFF_COL + 850000)         // 2 ints

__device__ __forceinline__ float bf2f(unsigned short u) {
    return __uint_as_float(((unsigned int)u) << 16);
}

// ---- dtype detection ----
__global__ void detect_kernel(const unsigned short* xr, const int* ei, int* flags) {
    __shared__ int c1, c2;
    if (threadIdx.x == 0) { c1 = 0; c2 = 0; }
    __syncthreads();
    int t = threadIdx.x;
    int l1 = 0, l2 = 0;
    for (int i = t; i < 2048; i += 256) {
        float v = bf2f(xr[i]);
        if (!(fabsf(v) <= 100.0f)) l1++;
        if (ei[2 * i + 1] != 0) l2++;
    }
    atomicAdd(&c1, l1);
    atomicAdd(&c2, l2);
    __syncthreads();
    if (t == 0) {
        flags[0] = (c1 > 16) ? 1 : 0;
        flags[1] = (c2 == 0) ? 1 : 0;
    }
}

struct ParamPtrs { const void* p[23]; };

__global__ void convert_kernel(ParamPtrs ps, float* dst, const int* flags) {
    const int sizes[23] = {100000, 256,128,256,128,128,128,128,128,
                           8192,64,8192,64,64,64,64,64,
                           128,2,128,2,2,2};
    int g = blockIdx.x * 256 + threadIdx.x;
    if (g >= N_PARAM_TOT) return;
    int t = 0, off = g;
    while (off >= sizes[t]) { off -= sizes[t]; t++; }
    float v;
    if (flags[0]) v = ((const float*)ps.p[t])[off];
    else          v = bf2f(((const unsigned short*)ps.p[t])[off]);
    dst[g] = v;
}

// ---- CSR build ----
__global__ void init_kernel(int* deg, float* stats) {
    int i = blockIdx.x * 256 + threadIdx.x;
    if (i < N_NODES) deg[i] = 1;            // self-loop pre-counted
    if (i < 512) stats[i] = 0.f;
}

__global__ void hist_kernel(const int* ei, int* deg, const int* flags) {
    int e = blockIdx.x * 256 + threadIdx.x;
    if (e >= N_E0) return;
    int dst = flags[1] ? ei[2 * (N_E0 + e)] : ei[N_E0 + e];
    atomicAdd(&deg[dst], 1);
}

__global__ void scan1_kernel(const int* deg, int* row_ptr, int* bsum) {
    __shared__ int sh[256];
    int i = blockIdx.x * 256 + threadIdx.x;
    int v = (i < N_NODES) ? deg[i] : 0;
    sh[threadIdx.x] = v;
    __syncthreads();
    for (int off = 1; off < 256; off <<= 1) {
        int t = (threadIdx.x >= off) ? sh[threadIdx.x - off] : 0;
        __syncthreads();
        sh[threadIdx.x] += t;
        __syncthreads();
    }
    if (i < N_NODES) row_ptr[i] = sh[threadIdx.x] - v;
    if (threadIdx.x == 255) bsum[blockIdx.x] = sh[255];
}

__global__ void scan2_kernel(int* bsum) {
    __shared__ int sh[256];
    int t = threadIdx.x;
    int v = (t < 196) ? bsum[t] : 0;
    sh[t] = v;
    __syncthreads();
    for (int off = 1; off < 256; off <<= 1) {
        int u = (t >= off) ? sh[t - off] : 0;
        __syncthreads();
        sh[t] += u;
        __syncthreads();
    }
    bsum[t] = sh[t] - v;
}

__global__ void scan3_kernel(int* row_ptr, int* cursor, const int* bsum) {
    int i = blockIdx.x * 256 + threadIdx.x;
    if (i < N_NODES) {
        int r = row_ptr[i] + bsum[blockIdx.x];
        row_ptr[i] = r;
        cursor[i] = r;
    }
    if (i == 0) row_ptr[N_NODES] = N_ET;
}

__global__ void scatter_kernel(const int* ei, int* cursor, int* col, const int* flags) {
    int e = blockIdx.x * 256 + threadIdx.x;
    if (e >= N_ET) return;
    int src, dst;
    if (e < N_E0) {
        int i64 = flags[1];
        if (i64) { src = ei[2 * e]; dst = ei[2 * (N_E0 + e)]; }
        else     { src = ei[e];     dst = ei[N_E0 + e]; }
    } else {
        src = dst = e - N_E0;
    }
    int pos = atomicAdd(&cursor[dst], 1);
    col[pos] = src;
}

// ---- layer 1 gather: H=8, C=16; wave/node, float2/lane, unroll-4 edges ----
__global__ void __launch_bounds__(256) gather1_kernel(
    const int* row_ptr, const int* col, const float* x,
    const float* W1l, const float* b1l, const float* W1r, const float* b1r,
    const float* att, const float* bias, float* C)
{
    int gid = blockIdx.x * 256 + threadIdx.x;
    int n = gid >> 6;
    int lane = threadIdx.x & 63;
    if (n >= N_NODES) return;
    float2 wl0 = *(const float2*)(W1l + 2 * lane);
    float2 wl1 = *(const float2*)(W1l + 128 + 2 * lane);
    float2 bl  = *(const float2*)(b1l + 2 * lane);
    float2 wr0 = *(const float2*)(W1r + 2 * lane);
    float2 wr1 = *(const float2*)(W1r + 128 + 2 * lane);
    float2 br  = *(const float2*)(b1r + 2 * lane);
    float2 at  = *(const float2*)(att + 2 * lane);
    float2 xd  = *(const float2*)(x + 2 * n);
    float xr0 = xd.x * wr0.x + xd.y * wr1.x + br.x;
    float xr1 = xd.x * wr0.y + xd.y * wr1.y + br.y;
    int base = row_ptr[n];
    int deg  = row_ptr[n + 1] - base;
    float acc0 = 0.f, acc1 = 0.f, den = 0.f;
    for (int j0 = 0; j0 < deg; j0 += 64) {
        int idx = j0 + lane;
        int msrc = (idx < deg) ? col[base + idx] : 0;
        int cnt = deg - j0; if (cnt > 64) cnt = 64;
        int j = 0;
        for (; j + 4 <= cnt; j += 4) {
            int s[4];
            #pragma unroll
            for (int u = 0; u < 4; u++) s[u] = __shfl(msrc, j + u, 64);
            float2 xs[4];
            #pragma unroll
            for (int u = 0; u < 4; u++) xs[u] = *(const float2*)(x + 2 * s[u]);
            float xl0[4], xl1[4], part[4];
            #pragma unroll
            for (int u = 0; u < 4; u++) {
                xl0[u] = xs[u].x * wl0.x + xs[u].y * wl1.x + bl.x;
                xl1[u] = xs[u].x * wl0.y + xs[u].y * wl1.y + bl.y;
                float z0 = xl0[u] + xr0; z0 = fmaxf(z0, 0.f) + 0.2f * fminf(z0, 0.f);
                float z1 = xl1[u] + xr1; z1 = fmaxf(z1, 0.f) + 0.2f * fminf(z1, 0.f);
                part[u] = z0 * at.x + z1 * at.y;
            }
            #pragma unroll
            for (int m = 1; m <= 4; m <<= 1) {
                #pragma unroll
                for (int u = 0; u < 4; u++) part[u] += __shfl_xor(part[u], m, 64);
            }
            #pragma unroll
            for (int u = 0; u < 4; u++) {
                float p = __expf(part[u]);
                acc0 += p * xl0[u]; acc1 += p * xl1[u]; den += p;
            }
        }
        for (; j < cnt; ++j) {
            int src = __shfl(msrc, j, 64);
            float2 xs = *(const float2*)(x + 2 * src);
            float xl0s = xs.x * wl0.x + xs.y * wl1.x + bl.x;
            float xl1s = xs.x * wl0.y + xs.y * wl1.y + bl.y;
            float z0 = xl0s + xr0; z0 = fmaxf(z0, 0.f) + 0.2f * fminf(z0, 0.f);
            float z1 = xl1s + xr1; z1 = fmaxf(z1, 0.f) + 0.2f * fminf(z1, 0.f);
            float part = z0 * at.x + z1 * at.y;
            part += __shfl_xor(part, 1, 64);
            part += __shfl_xor(part, 2, 64);
            part += __shfl_xor(part, 4, 64);
            float p = __expf(part);
            acc0 += p * xl0s; acc1 += p * xl1s; den += p;
        }
    }
    float inv = 1.f / den;
    float2 bi = *(const float2*)(bias + 2 * lane);
    float2 outv; outv.x = acc0 * inv + bi.x; outv.y = acc1 * inv + bi.y;
    *(float2*)(C + n * 128 + 2 * lane) = outv;
}

// ---- BN stats (layer 1, 128 ch) ----
__global__ void stats1_kernel(const float* C, float* stats) {
    int tid = threadIdx.x;
    int c = tid & 127, half = tid >> 7;
    float sum = 0.f, sq = 0.f;
    for (int r = blockIdx.x * 2 + half; r < N_NODES; r += 240) {
        float v = C[r * 128 + c];
        sum += v; sq += v * v;
    }
    __shared__ float ls[256], lq[256];
    ls[tid] = sum; lq[tid] = sq;
    __syncthreads();
    if (tid < 128) {
        atomicAdd(&stats[c],       ls[tid] + ls[tid + 128]);
        atomicAdd(&stats[128 + c], lq[tid] + lq[tid + 128]);
    }
}

// ---- layer 2 linear, register-tiled, fused BN1+ELU on staging ----
// 64 nodes/block; thread tile = 4 nodes x 4 ch x 2 matrices.
__global__ void __launch_bounds__(256) lin2_kernel(
    const float* C, const float* stats, const float* g1, const float* be1,
    const float* Wl, const float* bl, const float* Wr, const float* br,
    float* xl2, float* xr2)
{
    __shared__ float h[64 * 132];   // +4 pad: rows shift 4 banks each
    int tid = threadIdx.x;
    int nb = blockIdx.x * 64;
    for (int i = tid; i < 64 * 128; i += 256) {
        int ni = i >> 7, k = i & 127;
        int n = nb + ni;
        float v = 0.f;
        if (n < N_NODES) {
            float val = C[n * 128 + k];
            float mu = stats[k] * (1.0f / N_NODES);
            float var = stats[128 + k] * (1.0f / N_NODES) - mu * mu;
            float sc = g1[k] * rsqrtf(var + EPSBN);
            float b = (val - mu) * sc + be1[k];
            v = b > 0.f ? b : __expf(b) - 1.f;   // ELU
        }
        h[ni * 132 + k] = v;
    }
    __syncthreads();
    int kt = (tid & 15) * 4;
    int nt = (tid >> 4) * 4;
    float accl[4][4], accr[4][4];
    #pragma unroll
    for (int i = 0; i < 4; i++) {
        #pragma unroll
        for (int k = 0; k < 4; k++) { accl[i][k] = 0.f; accr[i][k] = 0.f; }
    }
    for (int j = 0; j < 128; j += 4) {
        float4 hv[4];
        #pragma unroll
        for (int i = 0; i < 4; i++)
            hv[i] = *(const float4*)&h[(nt + i) * 132 + j];
        #pragma unroll
        for (int jj = 0; jj < 4; jj++) {
            float4 wl4 = *(const float4*)&Wl[(j + jj) * 64 + kt];
            float4 wr4 = *(const float4*)&Wr[(j + jj) * 64 + kt];
            #pragma unroll
            for (int i = 0; i < 4; i++) {
                float hvv = (jj == 0) ? hv[i].x : (jj == 1) ? hv[i].y :
                            (jj == 2) ? hv[i].z : hv[i].w;
                accl[i][0] += hvv * wl4.x; accl[i][1] += hvv * wl4.y;
                accl[i][2] += hvv * wl4.z; accl[i][3] += hvv * wl4.w;
                accr[i][0] += hvv * wr4.x; accr[i][1] += hvv * wr4.y;
                accr[i][2] += hvv * wr4.z; accr[i][3] += hvv * wr4.w;
            }
        }
    }
    float4 blv = *(const float4*)&bl[kt];
    float4 brv = *(const float4*)&br[kt];
    #pragma unroll
    for (int i = 0; i < 4; i++) {
        int n = nb + nt + i;
        if (n < N_NODES) {
            float4 o;
            o.x = accl[i][0] + blv.x; o.y = accl[i][1] + blv.y;
            o.z = accl[i][2] + blv.z; o.w = accl[i][3] + blv.w;
            *(float4*)&xl2[n * 64 + kt] = o;
            o.x = accr[i][0] + brv.x; o.y = accr[i][1] + brv.y;
            o.z = accr[i][2] + brv.z; o.w = accr[i][3] + brv.w;
            *(float4*)&xr2[n * 64 + kt] = o;
        }
    }
}

// ---- layer 2 gather: H=4, C=16; wave/node, unroll-4 edges ----
__global__ void __launch_bounds__(256) gather2_kernel(
    const int* row_ptr, const int* col, const float* xl2, const float* xr2,
    const float* att, const float* bias, float* C)
{
    int gid = blockIdx.x * 256 + threadIdx.x;
    int n = gid >> 6;
    int lane = threadIdx.x & 63;
    if (n >= N_NODES) return;
    float xrv = xr2[n * 64 + lane];
    float atv = att[lane];
    int base = row_ptr[n];
    int deg  = row_ptr[n + 1] - base;
    float acc = 0.f, den = 0.f;
    for (int j0 = 0; j0 < deg; j0 += 64) {
        int idx = j0 + lane;
        int msrc = (idx < deg) ? col[base + idx] : 0;
        int cnt = deg - j0; if (cnt > 64) cnt = 64;
        int j = 0;
        for (; j + 4 <= cnt; j += 4) {
            int s[4];
            #pragma unroll
            for (int u = 0; u < 4; u++) s[u] = __shfl(msrc, j + u, 64);
            float xlv[4], part[4];
            #pragma unroll
            for (int u = 0; u < 4; u++) xlv[u] = xl2[s[u] * 64 + lane];
            #pragma unroll
            for (int u = 0; u < 4; u++) {
                float z = xlv[u] + xrv; z = fmaxf(z, 0.f) + 0.2f * fminf(z, 0.f);
                part[u] = z * atv;
            }
            #pragma unroll
            for (int m = 1; m <= 8; m <<= 1) {
                #pragma unroll
                for (int u = 0; u < 4; u++) part[u] += __shfl_xor(part[u], m, 64);
            }
            #pragma unroll
            for (int u = 0; u < 4; u++) {
                float p = __expf(part[u]);
                acc += p * xlv[u]; den += p;
            }
        }
        for (; j < cnt; ++j) {
            int src = __shfl(msrc, j, 64);
            float xlv = xl2[src * 64 + lane];
            float z = xlv + xrv; z = fmaxf(z, 0.f) + 0.2f * fminf(z, 0.f);
            float part = z * atv;
            part += __shfl_xor(part, 1, 64);
            part += __shfl_xor(part, 2, 64);
            part += __shfl_xor(part, 4, 64);
            part += __shfl_xor(part, 8, 64);
            float p = __expf(part);
            acc += p * xlv; den += p;
        }
    }
    C[n * 64 + lane] = acc / den + bias[lane];
}

__global__ void stats2_kernel(const float* C, float* stats) {
    int tid = threadIdx.x;
    int c = tid & 63, q = tid >> 6;
    float sum = 0.f, sq = 0.f;
    for (int r = blockIdx.x * 4 + q; r < N_NODES; r += 480) {
        float v = C[r * 64 + c];
        sum += v; sq += v * v;
    }
    __shared__ float ls[256], lq[256];
    ls[tid] = sum; lq[tid] = sq;
    __syncthreads();
    if (tid < 64) {
        atomicAdd(&stats[c],      ls[tid] + ls[tid + 64] + ls[tid + 128] + ls[tid + 192]);
        atomicAdd(&stats[64 + c], lq[tid] + lq[tid + 64] + lq[tid + 128] + lq[tid + 192]);
    }
}

// ---- layer 3 linear: wave/node butterfly reduce, fused BN2+ELU ----
__global__ void __launch_bounds__(256) lin3_kernel(
    const float* C, const float* stats2, const float* g2, const float* be2,
    const float* Wl, const float* bl, const float* Wr, const float* br,
    float* xl3, float* xr3)
{
    int gid = blockIdx.x * 256 + threadIdx.x;
    int n = gid >> 6;
    int lane = threadIdx.x & 63;
    if (n >= N_NODES) return;
    float mu = stats2[lane] * (1.0f / N_NODES);
    float var = stats2[64 + lane] * (1.0f / N_NODES) - mu * mu;
    float sc = g2[lane] * rsqrtf(var + EPSBN);
    float of = be2[lane] - mu * sc;
    float v = C[n * 64 + lane] * sc + of;
    float h = v > 0.f ? v : __expf(v) - 1.f;   // ELU
    float2 wlv = *(const float2*)(Wl + 2 * lane);
    float2 wrv = *(const float2*)(Wr + 2 * lane);
    float a0 = h * wlv.x, a1 = h * wlv.y;
    float r0 = h * wrv.x, r1 = h * wrv.y;
    #pragma unroll
    for (int m = 1; m < 64; m <<= 1) {
        a0 += __shfl_xor(a0, m, 64);
        a1 += __shfl_xor(a1, m, 64);
        r0 += __shfl_xor(r0, m, 64);
        r1 += __shfl_xor(r1, m, 64);
    }
    if (lane == 0) {
        xl3[2 * n]     = a0 + bl[0];
        xl3[2 * n + 1] = a1 + bl[1];
        xr3[2 * n]     = r0 + br[0];
        xr3[2 * n + 1] = r1 + br[1];
    }
}

// ---- layer 3 gather: H=1, C=2; thread/node, unroll-4, fused output ----
__global__ void gather3_kernel(const int* row_ptr, const int* col,
                               const float* xl3, const float* xr3,
                               const float* att, const float* bias,
                               void* out, const int* flags) {
    int n = blockIdx.x * 256 + threadIdx.x;
    if (n >= N_NODES) return;
    float a0 = att[0], a1 = att[1];
    float xr0 = xr3[2 * n], xr1 = xr3[2 * n + 1];
    float acc0 = 0.f, acc1 = 0.f, den = 0.f;
    int e0 = row_ptr[n], e1 = row_ptr[n + 1];
    int e = e0;
    for (; e + 4 <= e1; e += 4) {
        int s[4];
        #pragma unroll
        for (int u = 0; u < 4; u++) s[u] = col[e + u];
        float2 xs[4];
        #pragma unroll
        for (int u = 0; u < 4; u++) xs[u] = *(const float2*)(xl3 + 2 * s[u]);
        #pragma unroll
        for (int u = 0; u < 4; u++) {
            float z0 = xs[u].x + xr0; z0 = fmaxf(z0, 0.f) + 0.2f * fminf(z0, 0.f);
            float z1 = xs[u].y + xr1; z1 = fmaxf(z1, 0.f) + 0.2f * fminf(z1, 0.f);
            float p = __expf(z0 * a0 + z1 * a1);
            acc0 += p * xs[u].x; acc1 += p * xs[u].y; den += p;
        }
    }
    for (; e < e1; ++e) {
        int src = col[e];
        float2 xs = *(const float2*)(xl3 + 2 * src);
        float z0 = xs.x + xr0; z0 = fmaxf(z0, 0.f) + 0.2f * fminf(z0, 0.f);
        float z1 = xs.y + xr1; z1 = fmaxf(z1, 0.f) + 0.2f * fminf(z1, 0.f);
        float p = __expf(z0 * a0 + z1 * a1);
        acc0 += p * xs.x; acc1 += p * xs.y; den += p;
    }
    float inv = 1.f / den;
    float v0 = acc0 * inv + bias[0];
    float v1 = acc1 * inv + bias[1];
    if (flags[0]) {
        ((float*)out)[2 * n] = v0;
        ((float*)out)[2 * n + 1] = v1;
    } else {
        ((__hip_bfloat16*)out)[2 * n] = __float2bfloat16(v0);
        ((__hip_bfloat16*)out)[2 * n + 1] = __float2bfloat16(v1);
    }
}

extern "C" void kernel_launch(void* const* d_in, const int* in_sizes, int n_in,
                              void* d_out, int out_size, void* d_ws, size_t ws_size,
                              hipStream_t stream) {
    float* W = (float*)d_ws;
    float* C = W + OFF_C;
    float* A = W + OFF_A;
    float* B = W + OFF_B;
    float* STATS = W + OFF_STATS;
    float* P = W + OFF_P;
    int* ROWPTR = (int*)(W + OFF_ROWPTR);
    int* DEG    = (int*)(W + OFF_DEG);
    int* CURSOR = (int*)(W + OFF_CURSOR);
    int* BSUM   = (int*)(W + OFF_BSUM);
    int* COL    = (int*)(W + OFF_COL);
    int* FLAGS  = (int*)(W + OFF_FLAGS);

    const int* ei = (const int*)d_in[1];

    float* Px  = P;
    float* W1l = Px + 100000; float* b1l = W1l + 256; float* W1r = b1l + 128; float* b1r = W1r + 256;
    float* a1  = b1r + 128;   float* bias1 = a1 + 128; float* g1 = bias1 + 128; float* be1 = g1 + 128;
    float* W2l = be1 + 128;   float* b2l = W2l + 8192; float* W2r = b2l + 64;  float* b2r = W2r + 8192;
    float* a2  = b2r + 64;    float* bias2 = a2 + 64;  float* g2 = bias2 + 64; float* be2 = g2 + 64;
    float* W3l = be2 + 64;    float* b3l = W3l + 128;  float* W3r = b3l + 2;   float* b3r = W3r + 128;
    float* a3  = b3r + 2;     float* bias3 = a3 + 2;

    detect_kernel<<<1, 256, 0, stream>>>((const unsigned short*)d_in[0], ei, FLAGS);

    ParamPtrs ps;
    ps.p[0] = d_in[0];
    for (int j = 1; j < 23; j++) ps.p[j] = d_in[j + 1];
    convert_kernel<<<(N_PARAM_TOT + 255) / 256, 256, 0, stream>>>(ps, P, FLAGS);

    // ---- CSR build (reused by all 3 layers) ----
    init_kernel<<<196, 256, 0, stream>>>(DEG, STATS);
    hist_kernel<<<(N_E0 + 255) / 256, 256, 0, stream>>>(ei, DEG, FLAGS);
    scan1_kernel<<<196, 256, 0, stream>>>(DEG, ROWPTR, BSUM);
    scan2_kernel<<<1, 256, 0, stream>>>(BSUM);
    scan3_kernel<<<196, 256, 0, stream>>>(ROWPTR, CURSOR, BSUM);
    scatter_kernel<<<(N_ET + 255) / 256, 256, 0, stream>>>(ei, CURSOR, COL, FLAGS);

    // ---- layer 1 ----
    gather1_kernel<<<N_NODES * 64 / 256, 256, 0, stream>>>(ROWPTR, COL, Px, W1l, b1l, W1r, b1r, a1, bias1, C);
    stats1_kernel<<<120, 256, 0, stream>>>(C, STATS);

    // ---- layer 2 (BN1+ELU fused into lin2 staging) ----
    lin2_kernel<<<(N_NODES + 63) / 64, 256, 0, stream>>>(C, STATS, g1, be1, W2l, b2l, W2r, b2r, A, B);
    gather2_kernel<<<N_NODES * 64 / 256, 256, 0, stream>>>(ROWPTR, COL, A, B, a2, bias2, C);
    stats2_kernel<<<120, 256, 0, stream>>>(C, STATS + 256);

    // ---- layer 3 (BN2+ELU fused into lin3) ----
    lin3_kernel<<<N_NODES * 64 / 256, 256, 0, stream>>>(C, STATS + 256, g2, be2, W3l, b3l, W3r, b3r, A, B);
    gather3_kernel<<<196, 256, 0, stream>>>(ROWPTR, COL, A, B, a3, bias3, d_out, FLAGS);
}

// Round 4
// 432.463 us; speedup vs baseline: 3.4166x; 1.0494x over previous
//
#include <hip/hip_runtime.h>
#include <hip/hip_bf16.h>

#define N_NODES 50000
#define N_E0    800000
#define N_ET    850000
#define EPSBN   1e-5f
#define LOG2E   1.4426950408889634f

// ---- workspace layout (32-bit word offsets) ----
#define OFF_C 0
#define OFF_A (128*N_NODES)
#define OFF_B (192*N_NODES)
#define OFF_STATS (256*N_NODES)
#define OFF_P (OFF_STATS + 512)
#define N_PARAM_TOT 118312
#define OFF_ROWPTR (OFF_P + N_PARAM_TOT)      // 50001 ints
#define OFF_DEG    (OFF_ROWPTR + 50001)       // 50000 ints
#define OFF_CURSOR (OFF_DEG + 50000)          // 50000 ints
#define OFF_BSUM   (OFF_CURSOR + 50000)       // 256 ints
#define OFF_COL    (OFF_BSUM + 256)           // 850000 + 64 pad ints
#define OFF_FLAGS  (OFF_COL + 850064)         // 2 ints

__device__ __forceinline__ float bf2f(unsigned short u) {
    return __uint_as_float(((unsigned int)u) << 16);
}

// ---- prep: dtype detect (block 0) + deg/stats init (all blocks) ----
__global__ void prep_kernel(const unsigned short* xr, const int* ei, int* flags,
                            int* deg, float* stats) {
    int i = blockIdx.x * 256 + threadIdx.x;
    if (i < N_NODES) deg[i] = 1;            // self-loop pre-counted
    if (i < 512) stats[i] = 0.f;
    if (blockIdx.x == 0) {
        __shared__ int c1, c2;
        if (threadIdx.x == 0) { c1 = 0; c2 = 0; }
        __syncthreads();
        int t = threadIdx.x;
        int l1 = 0, l2 = 0;
        for (int k = t; k < 2048; k += 256) {
            float v = bf2f(xr[k]);
            if (!(fabsf(v) <= 100.0f)) l1++;
            if (ei[2 * k + 1] != 0) l2++;
        }
        atomicAdd(&c1, l1);
        atomicAdd(&c2, l2);
        __syncthreads();
        if (t == 0) {
            flags[0] = (c1 > 16) ? 1 : 0;   // 1 => inputs are f32
            flags[1] = (c2 == 0) ? 1 : 0;   // 1 => edge_index is int64
        }
    }
}

struct ParamPtrs { const void* p[23]; };

// stage f32 params; att vectors (t=5,13,21) pre-scaled by log2e so softmax uses exp2
__global__ void convert_kernel(ParamPtrs ps, float* dst, const int* flags) {
    const int sizes[23] = {100000, 256,128,256,128,128,128,128,128,
                           8192,64,8192,64,64,64,64,64,
                           128,2,128,2,2,2};
    int g = blockIdx.x * 256 + threadIdx.x;
    if (g >= N_PARAM_TOT) return;
    int t = 0, off = g;
    while (off >= sizes[t]) { off -= sizes[t]; t++; }
    float v;
    if (flags[0]) v = ((const float*)ps.p[t])[off];
    else          v = bf2f(((const unsigned short*)ps.p[t])[off]);
    if (t == 5 || t == 13 || t == 21) v *= LOG2E;
    dst[g] = v;
}

// ---- XCD-striped histogram: stripe s handles dst in [6250s, 6250(s+1)) ----
#define H_CHUNK 2048
__global__ void hist_kernel(const int* ei, int* deg, const int* flags) {
    int stripe = blockIdx.x & 7;
    int base_e = (blockIdx.x >> 3) * H_CHUNK;
    int i64 = flags[1];
    for (int i = 0; i < H_CHUNK; i += 256) {
        int e = base_e + i + threadIdx.x;
        if (e < N_E0) {
            int dst = i64 ? ei[2 * (N_E0 + e)] : ei[N_E0 + e];
            if (dst / 6250 == stripe) atomicAdd(&deg[dst], 1);
        }
    }
}

__global__ void scan1_kernel(const int* deg, int* row_ptr, int* bsum) {
    __shared__ int sh[256];
    int i = blockIdx.x * 256 + threadIdx.x;
    int v = (i < N_NODES) ? deg[i] : 0;
    sh[threadIdx.x] = v;
    __syncthreads();
    for (int off = 1; off < 256; off <<= 1) {
        int t = (threadIdx.x >= off) ? sh[threadIdx.x - off] : 0;
        __syncthreads();
        sh[threadIdx.x] += t;
        __syncthreads();
    }
    if (i < N_NODES) row_ptr[i] = sh[threadIdx.x] - v;
    if (threadIdx.x == 255) bsum[blockIdx.x] = sh[255];
}

// ---- merged scan2+scan3: each block re-scans bsum locally ----
__global__ void scan23_kernel(int* row_ptr, int* cursor, const int* bsum) {
    __shared__ int sh[256];
    int t = threadIdx.x;
    int v = (t < 196) ? bsum[t] : 0;
    sh[t] = v;
    __syncthreads();
    for (int off = 1; off < 256; off <<= 1) {
        int u = (t >= off) ? sh[t - off] : 0;
        __syncthreads();
        sh[t] += u;
        __syncthreads();
    }
    int prefix = (blockIdx.x == 0) ? 0 : sh[blockIdx.x - 1];
    int i = blockIdx.x * 256 + t;
    if (i < N_NODES) {
        int r = row_ptr[i] + prefix;
        row_ptr[i] = r;
        cursor[i] = r;
    }
    if (i == 0) row_ptr[N_NODES] = N_ET;
}

// ---- XCD-striped scatter: col writes confined to one 425KB stripe per block ----
#define SC_CHUNK 2048
__global__ void scatter_kernel(const int* ei, int* cursor, int* col, const int* flags) {
    int stripe = blockIdx.x & 7;
    int base_e = (blockIdx.x >> 3) * SC_CHUNK;
    int i64 = flags[1];
    for (int i = 0; i < SC_CHUNK; i += 256) {
        int e = base_e + i + threadIdx.x;
        if (e >= N_ET) continue;
        int src, dst;
        if (e < N_E0) {
            dst = i64 ? ei[2 * (N_E0 + e)] : ei[N_E0 + e];
            if (dst / 6250 != stripe) continue;
            src = i64 ? ei[2 * e] : ei[e];
        } else {
            src = dst = e - N_E0;
            if (dst / 6250 != stripe) continue;
        }
        int pos = atomicAdd(&cursor[dst], 1);
        col[pos] = src;
    }
}

// ---- layer 1 gather: H=8, C=16; wave/node, 2ch/lane, unroll-8, scalar src path ----
__global__ void __launch_bounds__(256) gather1_kernel(
    const int* row_ptr, const int* col, const float* x,
    const float* W1l, const float* b1l, const float* W1r, const float* b1r,
    const float* att, const float* bias, float* C)
{
    int gid = blockIdx.x * 256 + threadIdx.x;
    int n = gid >> 6;
    int lane = threadIdx.x & 63;
    if (n >= N_NODES) return;
    float2 wl0 = *(const float2*)(W1l + 2 * lane);
    float2 wl1 = *(const float2*)(W1l + 128 + 2 * lane);
    float2 bl  = *(const float2*)(b1l + 2 * lane);
    float2 wr0 = *(const float2*)(W1r + 2 * lane);
    float2 wr1 = *(const float2*)(W1r + 128 + 2 * lane);
    float2 br  = *(const float2*)(b1r + 2 * lane);
    float2 at  = *(const float2*)(att + 2 * lane);   // pre-scaled by log2e
    float2 xd  = *(const float2*)(x + 2 * n);
    float xr0 = fmaf(xd.x, wr0.x, fmaf(xd.y, wr1.x, br.x));
    float xr1 = fmaf(xd.x, wr0.y, fmaf(xd.y, wr1.y, br.y));
    int base = __builtin_amdgcn_readfirstlane(row_ptr[n]);
    int deg  = __builtin_amdgcn_readfirstlane(row_ptr[n + 1]) - base;
    float acc0 = 0.f, acc1 = 0.f, den = 0.f;
    for (int j0 = 0; j0 < deg; j0 += 64) {
        int cnt = deg - j0; if (cnt > 64) cnt = 64;
        int msrc = col[base + j0 + lane];   // COL padded by 64: unmasked OK
        int j = 0;
        for (; j + 8 <= cnt; j += 8) {
            int s[8];
            #pragma unroll
            for (int u = 0; u < 8; u++) s[u] = __builtin_amdgcn_readlane(msrc, j + u);
            float2 xs[8];
            #pragma unroll
            for (int u = 0; u < 8; u++) xs[u] = *(const float2*)(x + 2 * s[u]);
            float xl0[8], xl1[8], part[8];
            #pragma unroll
            for (int u = 0; u < 8; u++) {
                xl0[u] = fmaf(xs[u].x, wl0.x, fmaf(xs[u].y, wl1.x, bl.x));
                xl1[u] = fmaf(xs[u].x, wl0.y, fmaf(xs[u].y, wl1.y, bl.y));
                float z0 = xl0[u] + xr0; z0 = fmaxf(z0, 0.f) + 0.2f * fminf(z0, 0.f);
                float z1 = xl1[u] + xr1; z1 = fmaxf(z1, 0.f) + 0.2f * fminf(z1, 0.f);
                part[u] = fmaf(z0, at.x, z1 * at.y);
            }
            #pragma unroll
            for (int m = 1; m <= 4; m <<= 1) {
                #pragma unroll
                for (int u = 0; u < 8; u++) part[u] += __shfl_xor(part[u], m, 64);
            }
            #pragma unroll
            for (int u = 0; u < 8; u++) {
                float p = exp2f(part[u]);
                acc0 = fmaf(p, xl0[u], acc0);
                acc1 = fmaf(p, xl1[u], acc1);
                den += p;
            }
        }
        for (; j < cnt; ++j) {
            int s0 = __builtin_amdgcn_readlane(msrc, j);
            float2 xs = *(const float2*)(x + 2 * s0);
            float xl0s = fmaf(xs.x, wl0.x, fmaf(xs.y, wl1.x, bl.x));
            float xl1s = fmaf(xs.x, wl0.y, fmaf(xs.y, wl1.y, bl.y));
            float z0 = xl0s + xr0; z0 = fmaxf(z0, 0.f) + 0.2f * fminf(z0, 0.f);
            float z1 = xl1s + xr1; z1 = fmaxf(z1, 0.f) + 0.2f * fminf(z1, 0.f);
            float part = fmaf(z0, at.x, z1 * at.y);
            part += __shfl_xor(part, 1, 64);
            part += __shfl_xor(part, 2, 64);
            part += __shfl_xor(part, 4, 64);
            float p = exp2f(part);
            acc0 = fmaf(p, xl0s, acc0);
            acc1 = fmaf(p, xl1s, acc1);
            den += p;
        }
    }
    float inv = 1.f / den;
    float2 bi = *(const float2*)(bias + 2 * lane);
    float2 outv;
    outv.x = fmaf(acc0, inv, bi.x);
    outv.y = fmaf(acc1, inv, bi.y);
    *(float2*)(C + n * 128 + 2 * lane) = outv;
}

// ---- BN stats (layer 1, 128 ch) ----
__global__ void stats1_kernel(const float* C, float* stats) {
    int tid = threadIdx.x;
    int c = tid & 127, half = tid >> 7;
    float sum = 0.f, sq = 0.f;
    for (int r = blockIdx.x * 2 + half; r < N_NODES; r += 240) {
        float v = C[r * 128 + c];
        sum += v; sq += v * v;
    }
    __shared__ float ls[256], lq[256];
    ls[tid] = sum; lq[tid] = sq;
    __syncthreads();
    if (tid < 128) {
        atomicAdd(&stats[c],       ls[tid] + ls[tid + 128]);
        atomicAdd(&stats[128 + c], lq[tid] + lq[tid + 128]);
    }
}

// ---- layer 2 linear, register-tiled, fused BN1+ELU on staging ----
__global__ void __launch_bounds__(256) lin2_kernel(
    const float* C, const float* stats, const float* g1, const float* be1,
    const float* Wl, const float* bl, const float* Wr, const float* br,
    float* xl2, float* xr2)
{
    __shared__ float h[64 * 132];
    int tid = threadIdx.x;
    int nb = blockIdx.x * 64;
    for (int i = tid; i < 64 * 128; i += 256) {
        int ni = i >> 7, k = i & 127;
        int n = nb + ni;
        float v = 0.f;
        if (n < N_NODES) {
            float val = C[n * 128 + k];
            float mu = stats[k] * (1.0f / N_NODES);
            float var = stats[128 + k] * (1.0f / N_NODES) - mu * mu;
            float sc = g1[k] * rsqrtf(var + EPSBN);
            float b = (val - mu) * sc + be1[k];
            v = b > 0.f ? b : __expf(b) - 1.f;   // ELU
        }
        h[ni * 132 + k] = v;
    }
    __syncthreads();
    int kt = (tid & 15) * 4;
    int nt = (tid >> 4) * 4;
    float accl[4][4], accr[4][4];
    #pragma unroll
    for (int i = 0; i < 4; i++) {
        #pragma unroll
        for (int k = 0; k < 4; k++) { accl[i][k] = 0.f; accr[i][k] = 0.f; }
    }
    for (int j = 0; j < 128; j += 4) {
        float4 hv[4];
        #pragma unroll
        for (int i = 0; i < 4; i++)
            hv[i] = *(const float4*)&h[(nt + i) * 132 + j];
        #pragma unroll
        for (int jj = 0; jj < 4; jj++) {
            float4 wl4 = *(const float4*)&Wl[(j + jj) * 64 + kt];
            float4 wr4 = *(const float4*)&Wr[(j + jj) * 64 + kt];
            #pragma unroll
            for (int i = 0; i < 4; i++) {
                float hvv = (jj == 0) ? hv[i].x : (jj == 1) ? hv[i].y :
                            (jj == 2) ? hv[i].z : hv[i].w;
                accl[i][0] += hvv * wl4.x; accl[i][1] += hvv * wl4.y;
                accl[i][2] += hvv * wl4.z; accl[i][3] += hvv * wl4.w;
                accr[i][0] += hvv * wr4.x; accr[i][1] += hvv * wr4.y;
                accr[i][2] += hvv * wr4.z; accr[i][3] += hvv * wr4.w;
            }
        }
    }
    float4 blv = *(const float4*)&bl[kt];
    float4 brv = *(const float4*)&br[kt];
    #pragma unroll
    for (int i = 0; i < 4; i++) {
        int n = nb + nt + i;
        if (n < N_NODES) {
            float4 o;
            o.x = accl[i][0] + blv.x; o.y = accl[i][1] + blv.y;
            o.z = accl[i][2] + blv.z; o.w = accl[i][3] + blv.w;
            *(float4*)&xl2[n * 64 + kt] = o;
            o.x = accr[i][0] + brv.x; o.y = accr[i][1] + brv.y;
            o.z = accr[i][2] + brv.z; o.w = accr[i][3] + brv.w;
            *(float4*)&xr2[n * 64 + kt] = o;
        }
    }
}

// ---- layer 2 gather: H=4, C=16; wave/node, unroll-8, scalar src path ----
__global__ void __launch_bounds__(256) gather2_kernel(
    const int* row_ptr, const int* col, const float* xl2, const float* xr2,
    const float* att, const float* bias, float* C)
{
    int gid = blockIdx.x * 256 + threadIdx.x;
    int n = gid >> 6;
    int lane = threadIdx.x & 63;
    if (n >= N_NODES) return;
    float xrv = xr2[n * 64 + lane];
    float atv = att[lane];                 // pre-scaled by log2e
    int base = __builtin_amdgcn_readfirstlane(row_ptr[n]);
    int deg  = __builtin_amdgcn_readfirstlane(row_ptr[n + 1]) - base;
    float acc = 0.f, den = 0.f;
    for (int j0 = 0; j0 < deg; j0 += 64) {
        int cnt = deg - j0; if (cnt > 64) cnt = 64;
        int msrc = col[base + j0 + lane];
        int j = 0;
        for (; j + 8 <= cnt; j += 8) {
            const float* rp[8];
            #pragma unroll
            for (int u = 0; u < 8; u++)
                rp[u] = xl2 + (size_t)__builtin_amdgcn_readlane(msrc, j + u) * 64;
            float xlv[8], part[8];
            #pragma unroll
            for (int u = 0; u < 8; u++) xlv[u] = rp[u][lane];
            #pragma unroll
            for (int u = 0; u < 8; u++) {
                float z = xlv[u] + xrv; z = fmaxf(z, 0.f) + 0.2f * fminf(z, 0.f);
                part[u] = z * atv;
            }
            #pragma unroll
            for (int m = 1; m <= 8; m <<= 1) {
                #pragma unroll
                for (int u = 0; u < 8; u++) part[u] += __shfl_xor(part[u], m, 64);
            }
            #pragma unroll
            for (int u = 0; u < 8; u++) {
                float p = exp2f(part[u]);
                acc = fmaf(p, xlv[u], acc);
                den += p;
            }
        }
        for (; j < cnt; ++j) {
            int s0 = __builtin_amdgcn_readlane(msrc, j);
            float xlv = xl2[(size_t)s0 * 64 + lane];
            float z = xlv + xrv; z = fmaxf(z, 0.f) + 0.2f * fminf(z, 0.f);
            float part = z * atv;
            part += __shfl_xor(part, 1, 64);
            part += __shfl_xor(part, 2, 64);
            part += __shfl_xor(part, 4, 64);
            part += __shfl_xor(part, 8, 64);
            float p = exp2f(part);
            acc = fmaf(p, xlv, acc);
            den += p;
        }
    }
    C[n * 64 + lane] = acc / den + bias[lane];
}

__global__ void stats2_kernel(const float* C, float* stats) {
    int tid = threadIdx.x;
    int c = tid & 63, q = tid >> 6;
    float sum = 0.f, sq = 0.f;
    for (int r = blockIdx.x * 4 + q; r < N_NODES; r += 480) {
        float v = C[r * 64 + c];
        sum += v; sq += v * v;
    }
    __shared__ float ls[256], lq[256];
    ls[tid] = sum; lq[tid] = sq;
    __syncthreads();
    if (tid < 64) {
        atomicAdd(&stats[c],      ls[tid] + ls[tid + 64] + ls[tid + 128] + ls[tid + 192]);
        atomicAdd(&stats[64 + c], lq[tid] + lq[tid + 64] + lq[tid + 128] + lq[tid + 192]);
    }
}

// ---- layer 3 linear: wave/node butterfly reduce, fused BN2+ELU ----
__global__ void __launch_bounds__(256) lin3_kernel(
    const float* C, const float* stats2, const float* g2, const float* be2,
    const float* Wl, const float* bl, const float* Wr, const float* br,
    float* xl3, float* xr3)
{
    int gid = blockIdx.x * 256 + threadIdx.x;
    int n = gid >> 6;
    int lane = threadIdx.x & 63;
    if (n >= N_NODES) return;
    float mu = stats2[lane] * (1.0f / N_NODES);
    float var = stats2[64 + lane] * (1.0f / N_NODES) - mu * mu;
    float sc = g2[lane] * rsqrtf(var + EPSBN);
    float of = be2[lane] - mu * sc;
    float v = C[n * 64 + lane] * sc + of;
    float h = v > 0.f ? v : __expf(v) - 1.f;   // ELU
    float2 wlv = *(const float2*)(Wl + 2 * lane);
    float2 wrv = *(const float2*)(Wr + 2 * lane);
    float a0 = h * wlv.x, a1 = h * wlv.y;
    float r0 = h * wrv.x, r1 = h * wrv.y;
    #pragma unroll
    for (int m = 1; m < 64; m <<= 1) {
        a0 += __shfl_xor(a0, m, 64);
        a1 += __shfl_xor(a1, m, 64);
        r0 += __shfl_xor(r0, m, 64);
        r1 += __shfl_xor(r1, m, 64);
    }
    if (lane == 0) {
        xl3[2 * n]     = a0 + bl[0];
        xl3[2 * n + 1] = a1 + bl[1];
        xr3[2 * n]     = r0 + br[0];
        xr3[2 * n + 1] = r1 + br[1];
    }
}

// ---- layer 3 gather: H=1, C=2; thread/node, unroll-4, fused output ----
__global__ void gather3_kernel(const int* row_ptr, const int* col,
                               const float* xl3, const float* xr3,
                               const float* att, const float* bias,
                               void* out, const int* flags) {
    int n = blockIdx.x * 256 + threadIdx.x;
    if (n >= N_NODES) return;
    float a0 = att[0], a1 = att[1];        // pre-scaled by log2e
    float xr0 = xr3[2 * n], xr1 = xr3[2 * n + 1];
    float acc0 = 0.f, acc1 = 0.f, den = 0.f;
    int e0 = row_ptr[n], e1 = row_ptr[n + 1];
    int e = e0;
    for (; e + 4 <= e1; e += 4) {
        int s[4];
        #pragma unroll
        for (int u = 0; u < 4; u++) s[u] = col[e + u];
        float2 xs[4];
        #pragma unroll
        for (int u = 0; u < 4; u++) xs[u] = *(const float2*)(xl3 + 2 * s[u]);
        #pragma unroll
        for (int u = 0; u < 4; u++) {
            float z0 = xs[u].x + xr0; z0 = fmaxf(z0, 0.f) + 0.2f * fminf(z0, 0.f);
            float z1 = xs[u].y + xr1; z1 = fmaxf(z1, 0.f) + 0.2f * fminf(z1, 0.f);
            float p = exp2f(fmaf(z0, a0, z1 * a1));
            acc0 += p * xs[u].x; acc1 += p * xs[u].y; den += p;
        }
    }
    for (; e < e1; ++e) {
        int src = col[e];
        float2 xs = *(const float2*)(xl3 + 2 * src);
        float z0 = xs.x + xr0; z0 = fmaxf(z0, 0.f) + 0.2f * fminf(z0, 0.f);
        float z1 = xs.y + xr1; z1 = fmaxf(z1, 0.f) + 0.2f * fminf(z1, 0.f);
        float p = exp2f(fmaf(z0, a0, z1 * a1));
        acc0 += p * xs.x; acc1 += p * xs.y; den += p;
    }
    float inv = 1.f / den;
    float v0 = acc0 * inv + bias[0];
    float v1 = acc1 * inv + bias[1];
    if (flags[0]) {
        ((float*)out)[2 * n] = v0;
        ((float*)out)[2 * n + 1] = v1;
    } else {
        ((__hip_bfloat16*)out)[2 * n] = __float2bfloat16(v0);
        ((__hip_bfloat16*)out)[2 * n + 1] = __float2bfloat16(v1);
    }
}

extern "C" void kernel_launch(void* const* d_in, const int* in_sizes, int n_in,
                              void* d_out, int out_size, void* d_ws, size_t ws_size,
                              hipStream_t stream) {
    float* W = (float*)d_ws;
    float* C = W + OFF_C;
    float* A = W + OFF_A;
    float* B = W + OFF_B;
    float* STATS = W + OFF_STATS;
    float* P = W + OFF_P;
    int* ROWPTR = (int*)(W + OFF_ROWPTR);
    int* DEG    = (int*)(W + OFF_DEG);
    int* CURSOR = (int*)(W + OFF_CURSOR);
    int* BSUM   = (int*)(W + OFF_BSUM);
    int* COL    = (int*)(W + OFF_COL);
    int* FLAGS  = (int*)(W + OFF_FLAGS);

    const int* ei = (const int*)d_in[1];

    float* Px  = P;
    float* W1l = Px + 100000; float* b1l = W1l + 256; float* W1r = b1l + 128; float* b1r = W1r + 256;
    float* a1  = b1r + 128;   float* bias1 = a1 + 128; float* g1 = bias1 + 128; float* be1 = g1 + 128;
    float* W2l = be1 + 128;   float* b2l = W2l + 8192; float* W2r = b2l + 64;  float* b2r = W2r + 8192;
    float* a2  = b2r + 64;    float* bias2 = a2 + 64;  float* g2 = bias2 + 64; float* be2 = g2 + 64;
    float* W3l = be2 + 64;    float* b3l = W3l + 128;  float* W3r = b3l + 2;   float* b3r = W3r + 128;
    float* a3  = b3r + 2;     float* bias3 = a3 + 2;

    prep_kernel<<<196, 256, 0, stream>>>((const unsigned short*)d_in[0], ei, FLAGS, DEG, STATS);

    ParamPtrs ps;
    ps.p[0] = d_in[0];
    for (int j = 1; j < 23; j++) ps.p[j] = d_in[j + 1];
    convert_kernel<<<(N_PARAM_TOT + 255) / 256, 256, 0, stream>>>(ps, P, FLAGS);

    // ---- CSR build (XCD-striped hist + scatter) ----
    hist_kernel<<<8 * ((N_E0 + H_CHUNK - 1) / H_CHUNK), 256, 0, stream>>>(ei, DEG, FLAGS);
    scan1_kernel<<<196, 256, 0, stream>>>(DEG, ROWPTR, BSUM);
    scan23_kernel<<<196, 256, 0, stream>>>(ROWPTR, CURSOR, BSUM);
    scatter_kernel<<<8 * ((N_ET + SC_CHUNK - 1) / SC_CHUNK), 256, 0, stream>>>(ei, CURSOR, COL, FLAGS);

    // ---- layer 1 ----
    gather1_kernel<<<N_NODES * 64 / 256, 256, 0, stream>>>(ROWPTR, COL, Px, W1l, b1l, W1r, b1r, a1, bias1, C);
    stats1_kernel<<<120, 256, 0, stream>>>(C, STATS);

    // ---- layer 2 (BN1+ELU fused into lin2 staging) ----
    lin2_kernel<<<(N_NODES + 63) / 64, 256, 0, stream>>>(C, STATS, g1, be1, W2l, b2l, W2r, b2r, A, B);
    gather2_kernel<<<N_NODES * 64 / 256, 256, 0, stream>>>(ROWPTR, COL, A, B, a2, bias2, C);
    stats2_kernel<<<120, 256, 0, stream>>>(C, STATS + 256);

    // ---- layer 3 (BN2+ELU fused into lin3) ----
    lin3_kernel<<<N_NODES * 64 / 256, 256, 0, stream>>>(C, STATS + 256, g2, be2, W3l, b3l, W3r, b3r, A, B);
    gather3_kernel<<<196, 256, 0, stream>>>(ROWPTR, COL, A, B, a3, bias3, d_out, FLAGS);
}